// Round 1
// baseline (75.639 us; speedup 1.0000x reference)
//
#include <hip/hip_runtime.h>

// RandomRectangleErasing: out[b,c,h,w] = (y0<=h<y0+hh && x0<=w<x0+ww) ? 0 : img[b,c,h,w]
// B=64, C=3, H=512, W=512, fp32. Memory-bound streaming op.

constexpr int B = 64, C = 3, H = 512, W = 512;
constexpr int VEC_PER_ROW = W / 4;                 // 128 float4 per row
constexpr int TOTAL_VEC   = B * C * H * VEC_PER_ROW; // 12,582,912 float4

__global__ __launch_bounds__(256) void erase_kernel(
    const float4* __restrict__ in, float4* __restrict__ out,
    const int* __restrict__ widths, const int* __restrict__ heights,
    const int* __restrict__ xs, const int* __restrict__ ys)
{
    for (int idx = blockIdx.x * blockDim.x + threadIdx.x; idx < TOTAL_VEC;
         idx += gridDim.x * blockDim.x) {
        // idx layout: [b*3+c][h][w/4], all power-of-two except /3
        const int img = idx >> 16;            // (H*W/4) = 65536 vec per image
        const int b   = img / 3;              // compiler emits magic-mul
        const int h   = (idx >> 7) & (H - 1);
        const int w   = (idx & (VEC_PER_ROW - 1)) << 2;

        const int x0 = xs[b];
        const int y0 = ys[b];
        const int x1 = x0 + widths[b];
        const int y1 = y0 + heights[b];

        const bool in_row = (h >= y0) && (h < y1);

        float4 v;
        if (in_row && (w >= x0) && (w + 4 <= x1)) {
            // whole float4 inside erased rect: skip the load entirely
            v = make_float4(0.f, 0.f, 0.f, 0.f);
        } else {
            v = in[idx];
            if (in_row) {
                if (w + 0 >= x0 && w + 0 < x1) v.x = 0.f;
                if (w + 1 >= x0 && w + 1 < x1) v.y = 0.f;
                if (w + 2 >= x0 && w + 2 < x1) v.z = 0.f;
                if (w + 3 >= x0 && w + 3 < x1) v.w = 0.f;
            }
        }
        out[idx] = v;
    }
}

extern "C" void kernel_launch(void* const* d_in, const int* in_sizes, int n_in,
                              void* d_out, int out_size, void* d_ws, size_t ws_size,
                              hipStream_t stream) {
    const float4* in      = (const float4*)d_in[0];
    const int*    widths  = (const int*)d_in[1];
    const int*    heights = (const int*)d_in[2];
    const int*    xs      = (const int*)d_in[3];
    const int*    ys      = (const int*)d_in[4];
    float4*       out     = (float4*)d_out;

    const int threads = 256;
    const int blocks  = 2048;   // 256 CU × 8 blocks; grid-stride covers the rest
    erase_kernel<<<blocks, threads, 0, stream>>>(in, out, widths, heights, xs, ys);
}